// Round 4
// baseline (666.168 us; speedup 1.0000x reference)
//
#include <hip/hip_runtime.h>
#include <math.h>

// DualAttention: B=64, S=2048, H=512, F=128, fp32 in/out.
#define NB 64
#define NS 2048
#define NH 512
#define NF 128
#define BS (NB * NS)

typedef __attribute__((ext_vector_type(8))) _Float16 f16x8;  // 4 VGPRs (MFMA A/B)
typedef __attribute__((ext_vector_type(4))) _Float16 f16x4;  // 8 B LDS store
typedef __attribute__((ext_vector_type(4))) float f32x4;     // MFMA C/D

__device__ inline float fast_tanh(float x) {
  float e = __expf(2.f * x);
  return 1.f - 2.f / (e + 1.f);
}
// fp32 -> fp16 hi + fp16 lo (2-term split, exact to ~2^-22 rel)
__device__ inline void split4h(float4 p, f16x4& hv, f16x4& lv) {
  hv.x = (_Float16)p.x; hv.y = (_Float16)p.y; hv.z = (_Float16)p.z; hv.w = (_Float16)p.w;
  lv.x = (_Float16)(p.x - (float)hv.x);
  lv.y = (_Float16)(p.y - (float)hv.y);
  lv.z = (_Float16)(p.z - (float)hv.z);
  lv.w = (_Float16)(p.w - (float)hv.w);
}

// ---------------------------------------------------------------------------
// Pack W [K,512] fp32 -> MFMA B-frag layout, SINGLE fp16 plane.
// frag f = kt*32+nt (one per 16x16x32 B tile); element f*64*8 + lane*8 + j
// holds W[k,n], k = kt*32+(lane>>4)*8+j, n = nt*16+(lane&15).
// ---------------------------------------------------------------------------
__global__ __launch_bounds__(256) void pack_w_kernel(
    const float* __restrict__ W, _Float16* __restrict__ out) {
  const int tid = blockIdx.x * 256 + threadIdx.x;
  const int j = tid & 7, l = (tid >> 3) & 63, nt = (tid >> 9) & 31, kt = tid >> 14;
  const int k = kt * 32 + (l >> 4) * 8 + j;
  const int n = nt * 16 + (l & 15);
  out[tid] = (_Float16)W[k * NH + n];
}

// ---------------------------------------------------------------------------
// Fused score GEMM, asymmetric fp16 split (A: hi+lo fp16, W: single fp16;
// 2 MFMA products ~ fp32 precision — W fp16 rounding gives ~1e-4 proj err):
//   score[r] = sum_n tanh((A[r,:] @ W[:,n]) + bias[n]) * pin[b,n]
// Block: 256 thr = 4 waves; M=64 rows, N=512; wave w owns cols [w*128,w*128+128),
// mt=4, nt=8, acc 128 regs -> 2 waves/SIMD (structural).
//
// JOURNAL:
//  R0 baseline (W depth-1, A depth-1): 183us, MfmaUtil 33%.
//  R1 FAILED: W depth-4 circular reg buffer -> 207us, MfmaUtil 28.5%.
//    vmcnt is in-order: waiting any W refill still drains the older kt-top A
//    prefetch; depth added copies/branches/barrier-drain for nothing. Reverted.
//  R3 (this): A prefetch 2-kt deep, named reg double-buffer qA/qB, kt loop
//    unrolled x2 (static indexing, no scratch). The A load now has ~2 kt
//    (~1300-1900 cy) in flight before its LDS store vs ~900 cy HBM latency;
//    the per-kt staging drain should vanish.
// ---------------------------------------------------------------------------
template <int K>
__global__ __launch_bounds__(256, 2) void score_mfma(
    const float* __restrict__ A, const _Float16* __restrict__ Wp,
    const float* __restrict__ bias, const float* __restrict__ pin,
    float* __restrict__ score) {
  constexpr int KT = K / 32;
  static_assert(KT % 2 == 0, "kt loop unrolled x2");
  __shared__ __align__(16) _Float16 lAhi[2][64 * 40];  // row stride 80 B (16B mult)
  __shared__ __align__(16) _Float16 lAlo[2][64 * 40];
  __shared__ float red[4 * 64];
  const int t = threadIdx.x;
  const int wave = t >> 6, lane = t & 63;
  const int row0 = blockIdx.x * 64;
  const int b = row0 >> 11;  // row0 / S
  const int nb = wave * 8;   // first ntile of this wave

  f32x4 acc[4][8];
#pragma unroll
  for (int mt = 0; mt < 4; ++mt)
#pragma unroll
    for (int nt = 0; nt < 8; ++nt) acc[mt][nt] = (f32x4)0.f;

  // staging: thread t loads float4 at rows {lr, lr+32}, col lc
  const int lr = t >> 3, lc = (t & 7) * 4;
  const float* Ab0 = A + (size_t)(row0 + lr) * K + lc;
  const float* Ab1 = Ab0 + (size_t)32 * K;
  const int fr = lane & 15, fq = lane >> 4;

  // W fragment stream (f16x8 = 16B units): frag f at unit f*64 + lane.
  // Depth-1 prefetch (R0 form — measured best).
  const f16x8* wp = (const f16x8*)Wp + (size_t)nb * 64 + lane;
  f16x8 wcur = *wp;

  // A-tile register double-buffer, 2 kt deep.
  float4 qA0, qA1, qB0, qB1;
  // prologue: issue tile-1 load first (max head start), then stage tile 0.
  qA0 = *(const float4*)(Ab0 + 32);
  qA1 = *(const float4*)(Ab1 + 32);
  {
    f16x4 hv, lv;
    split4h(*(const float4*)Ab0, hv, lv);
    *(f16x4*)&lAhi[0][lr * 40 + lc] = hv;
    *(f16x4*)&lAlo[0][lr * 40 + lc] = lv;
    split4h(*(const float4*)Ab1, hv, lv);
    *(f16x4*)&lAhi[0][(lr + 32) * 40 + lc] = hv;
    *(f16x4*)&lAlo[0][(lr + 32) * 40 + lc] = lv;
  }
  __syncthreads();

// 8 MFMA groups for tile ktv out of LDS buffer bufv (W stream advances).
#define GROUPS(ktv, bufv)                                                      \
  {                                                                            \
    f16x8 ah[4], al[4];                                                        \
    _Pragma("unroll") for (int mt = 0; mt < 4; ++mt) {                         \
      const int ra = (mt * 16 + fr) * 40 + fq * 8;                             \
      ah[mt] = *(const f16x8*)&lAhi[bufv][ra];                                 \
      al[mt] = *(const f16x8*)&lAlo[bufv][ra];                                 \
    }                                                                          \
    _Pragma("unroll") for (int nt = 0; nt < 8; ++nt) {                         \
      const int adv = (nt < 7) ? 64 : (((ktv) < KT - 1) ? 25 * 64 : 0);        \
      const f16x8 wnxt = wp[adv];                                              \
      _Pragma("unroll") for (int mt = 0; mt < 4; ++mt) {                       \
        acc[mt][nt] =                                                          \
            __builtin_amdgcn_mfma_f32_16x16x32_f16(ah[mt], wcur, acc[mt][nt], 0, 0, 0); \
        acc[mt][nt] =                                                          \
            __builtin_amdgcn_mfma_f32_16x16x32_f16(al[mt], wcur, acc[mt][nt], 0, 0, 0); \
      }                                                                        \
      wcur = wnxt;                                                             \
      wp += adv;                                                               \
    }                                                                          \
  }

// Split q0v/q1v (already resident ~2 kt) into LDS buffer bufv.
#define STAGE(q0v, q1v, bufv)                                                  \
  {                                                                            \
    f16x4 hv, lv;                                                              \
    split4h(q0v, hv, lv);                                                      \
    *(f16x4*)&lAhi[bufv][lr * 40 + lc] = hv;                                   \
    *(f16x4*)&lAlo[bufv][lr * 40 + lc] = lv;                                   \
    split4h(q1v, hv, lv);                                                      \
    *(f16x4*)&lAhi[bufv][(lr + 32) * 40 + lc] = hv;                            \
    *(f16x4*)&lAlo[bufv][(lr + 32) * 40 + lc] = lv;                            \
  }

  for (int kt = 0; kt < KT; kt += 2) {
    // even step: compute tile kt from buf0; issue load for tile kt+2.
    if (kt + 2 < KT) {
      qB0 = *(const float4*)(Ab0 + (kt + 2) * 32);
      qB1 = *(const float4*)(Ab1 + (kt + 2) * 32);
    }
    GROUPS(kt, 0)
    STAGE(qA0, qA1, 1)  // tile kt+1 (kt+1 <= KT-1 since KT even)
    __syncthreads();

    // odd step: compute tile kt+1 from buf1; issue load for tile kt+3.
    if (kt + 3 < KT) {
      qA0 = *(const float4*)(Ab0 + (kt + 3) * 32);
      qA1 = *(const float4*)(Ab1 + (kt + 3) * 32);
    }
    GROUPS(kt + 1, 1)
    if (kt + 2 < KT) STAGE(qB0, qB1, 0)
    __syncthreads();
  }
#undef GROUPS
#undef STAGE

  // Epilogue: tanh + weighted column-reduce over this wave's 128 cols.
  // C layout: col = (nb+nt)*16 + fr ; row = mt*16 + fq*4 + r.
  float ps[4][4];
#pragma unroll
  for (int mt = 0; mt < 4; ++mt)
#pragma unroll
    for (int r = 0; r < 4; ++r) ps[mt][r] = 0.f;
#pragma unroll
  for (int nt = 0; nt < 8; ++nt) {
    const int col = (nb + nt) * 16 + fr;
    const float bi = bias[col], pi = pin[b * NH + col];
#pragma unroll
    for (int mt = 0; mt < 4; ++mt)
#pragma unroll
      for (int r = 0; r < 4; ++r)
        ps[mt][r] += fast_tanh(acc[mt][nt][r] + bi) * pi;
  }
#pragma unroll
  for (int m = 8; m; m >>= 1)
#pragma unroll
    for (int mt = 0; mt < 4; ++mt)
#pragma unroll
      for (int r = 0; r < 4; ++r) ps[mt][r] += __shfl_xor(ps[mt][r], m);
  if (fr == 0)
#pragma unroll
    for (int mt = 0; mt < 4; ++mt)
#pragma unroll
      for (int r = 0; r < 4; ++r) red[wave * 64 + mt * 16 + fq * 4 + r] = ps[mt][r];
  __syncthreads();
  if (t < 64) score[row0 + t] = red[t] + red[64 + t] + red[128 + t] + red[192 + t];
}

// ---------------------------------------------------------------------------
// proj_in: tanh(input @ W_{a,b} + b_{a,b}); grid (B,4).
// ---------------------------------------------------------------------------
__global__ __launch_bounds__(256) void proj_in_kernel(
    const float* __restrict__ input,
    const float* __restrict__ W_a, const float* __restrict__ b_a,
    const float* __restrict__ W_b, const float* __restrict__ b_b,
    float* __restrict__ pa, float* __restrict__ pb) {
  __shared__ float sin_[NH];
  const int b = blockIdx.x, part = blockIdx.y, t = threadIdx.x;
  const float* W  = (part < 2) ? W_a : W_b;
  const float* bi = (part < 2) ? b_a : b_b;
  float* out      = (part < 2) ? pa : pb;
  const int h = t + (part & 1) * 256;
  sin_[t] = input[b * NH + t];
  sin_[t + 256] = input[b * NH + t + 256];
  __syncthreads();
  float acc = 0.f;
  for (int k = 0; k < NH; ++k) acc = fmaf(sin_[k], W[k * NH + h], acc);
  out[b * NH + h] = tanhf(acc + bi[h]);
}

// ---------------------------------------------------------------------------
// gamma = softmax_S(score_a + score_b)
// ---------------------------------------------------------------------------
__global__ __launch_bounds__(256) void gamma_kernel(
    const float* __restrict__ sa, const float* __restrict__ sb,
    float* __restrict__ gamma) {
  const int b = blockIdx.x, t = threadIdx.x;
  __shared__ float swp[4];
  float v[8];
  float mx = -1e30f;
#pragma unroll
  for (int i = 0; i < 8; ++i) {
    const int s = b * NS + t + i * 256;
    v[i] = sa[s] + sb[s];
    mx = fmaxf(mx, v[i]);
  }
  const int wave = t >> 6, lane = t & 63;
#pragma unroll
  for (int off = 32; off; off >>= 1) mx = fmaxf(mx, __shfl_down(mx, off));
  if (lane == 0) swp[wave] = mx;
  __syncthreads();
  mx = fmaxf(fmaxf(swp[0], swp[1]), fmaxf(swp[2], swp[3]));
  __syncthreads();
  float sum = 0.f;
#pragma unroll
  for (int i = 0; i < 8; ++i) {
    v[i] = __expf(v[i] - mx);
    sum += v[i];
  }
#pragma unroll
  for (int off = 32; off; off >>= 1) sum += __shfl_down(sum, off);
  if (lane == 0) swp[wave] = sum;
  __syncthreads();
  const float inv = 1.f / (swp[0] + swp[1] + swp[2] + swp[3]);
#pragma unroll
  for (int i = 0; i < 8; ++i) gamma[b * NS + t + i * 256] = v[i] * inv;
}

// ---------------------------------------------------------------------------
// wctx partials: grid (B,8); float4 columns; wcp has 16 chunks per batch.
// ---------------------------------------------------------------------------
__global__ __launch_bounds__(256) void wctx_kernel(
    const float* __restrict__ ctx, const float* __restrict__ gamma,
    float* __restrict__ wcp) {
  const int b = blockIdx.x, ch = blockIdx.y, t = threadIdx.x;
  __shared__ float g[256];
  const int s0 = ch * 256;
  g[t] = gamma[b * NS + s0 + t];
  __syncthreads();
  const int sh = t >> 7, h4 = (t & 127) * 4;
  float4 acc = make_float4(0.f, 0.f, 0.f, 0.f);
  const float* base = ctx + (size_t)(b * NS + s0 + sh * 128) * NH + h4;
#pragma unroll 4
  for (int s = 0; s < 128; ++s) {
    const float gs = g[sh * 128 + s];
    const float4 c = *(const float4*)(base + (size_t)s * NH);
    acc.x = fmaf(gs, c.x, acc.x);
    acc.y = fmaf(gs, c.y, acc.y);
    acc.z = fmaf(gs, c.z, acc.z);
    acc.w = fmaf(gs, c.w, acc.w);
  }
  *(float4*)&wcp[(size_t)(b * 16 + ch * 2 + sh) * NH + h4] = acc;
}

// ---------------------------------------------------------------------------
// out: reduce 16 wcp chunks -> wc; h_tilde = tanh([wc,input] @ W_out). grid (B,2).
// ---------------------------------------------------------------------------
__global__ __launch_bounds__(256) void out_kernel(
    const float* __restrict__ wcp, const float* __restrict__ input,
    const float* __restrict__ W_out, float* __restrict__ out) {
  __shared__ float cat[2 * NH];
  const int b = blockIdx.x, half = blockIdx.y, t = threadIdx.x;
  for (int i = t; i < NH; i += 256) {
    float s = 0.f;
#pragma unroll
    for (int c = 0; c < 16; ++c) s += wcp[(size_t)(b * 16 + c) * NH + i];
    cat[i] = s;
    cat[NH + i] = input[b * NH + i];
  }
  __syncthreads();
  const int o = half * 256 + t;
  float acc = 0.f;
  for (int k = 0; k < 2 * NH; ++k) acc = fmaf(cat[k], W_out[(size_t)k * NH + o], acc);
  out[b * NH + o] = tanhf(acc);
}

// ---------------------------------------------------------------------------
extern "C" void kernel_launch(void* const* d_in, const int* in_sizes, int n_in,
                              void* d_out, int out_size, void* d_ws, size_t ws_size,
                              hipStream_t stream) {
  const float* input   = (const float*)d_in[0];
  const float* context = (const float*)d_in[1];
  const float* input_z = (const float*)d_in[2];
  const float* W_enc   = (const float*)d_in[3];
  const float* b_enc   = (const float*)d_in[4];
  const float* W_a     = (const float*)d_in[5];
  const float* b_a     = (const float*)d_in[6];
  const float* W_b     = (const float*)d_in[7];
  const float* b_b     = (const float*)d_in[8];
  const float* W_z     = (const float*)d_in[9];
  const float* b_z     = (const float*)d_in[10];
  const float* W_out   = (const float*)d_in[11];

  float* out = (float*)d_out;          // [0,32768): h_tilde, then gamma
  float* ws  = (float*)d_ws;
  float* pa  = ws;                     // 32768
  float* pb  = ws + 32768;             // 32768
  float* sa  = ws + 65536;             // B*S = 131072
  float* sb  = ws + 196608;            // B*S = 131072
  float* wcp = ws + 327680;            // 64*16*512 = 524288
  _Float16* WpE = (_Float16*)(ws + 851968);   // 512*512 f16 = 512 KB
  _Float16* WpZ = (_Float16*)(ws + 983040);   // 128*512 f16 = 128 KB
  float* gamma = out + NB * NH;

  hipLaunchKernelGGL(pack_w_kernel, dim3(NH * NH / 256), dim3(256), 0, stream,
                     W_enc, WpE);
  hipLaunchKernelGGL(pack_w_kernel, dim3(NF * NH / 256), dim3(256), 0, stream,
                     W_z, WpZ);
  hipLaunchKernelGGL(proj_in_kernel, dim3(NB, 4), dim3(256), 0, stream,
                     input, W_a, b_a, W_b, b_b, pa, pb);
  hipLaunchKernelGGL(score_mfma<NH>, dim3(BS / 64), dim3(256), 0, stream,
                     context, WpE, b_enc, pa, sa);
  hipLaunchKernelGGL(score_mfma<NF>, dim3(BS / 64), dim3(256), 0, stream,
                     input_z, WpZ, b_z, pb, sb);
  hipLaunchKernelGGL(gamma_kernel, dim3(NB), dim3(256), 0, stream, sa, sb, gamma);
  hipLaunchKernelGGL(wctx_kernel, dim3(NB, 8), dim3(256), 0, stream,
                     context, gamma, wcp);
  hipLaunchKernelGGL(out_kernel, dim3(NB, 2), dim3(256), 0, stream,
                     wcp, input, W_out, out);
}

// Round 5
// 640.502 us; speedup vs baseline: 1.0401x; 1.0401x over previous
//
#include <hip/hip_runtime.h>
#include <math.h>

// DualAttention: B=64, S=2048, H=512, F=128, fp32 in/out.
#define NB 64
#define NS 2048
#define NH 512
#define NF 128
#define BS (NB * NS)

typedef __attribute__((ext_vector_type(8))) _Float16 f16x8;  // 4 VGPRs (MFMA A/B)
typedef __attribute__((ext_vector_type(4))) _Float16 f16x4;  // 8 B LDS store
typedef __attribute__((ext_vector_type(4))) float f32x4;     // MFMA C/D

__device__ inline float fast_tanh(float x) {
  float e = __expf(2.f * x);
  return 1.f - 2.f / (e + 1.f);
}
// fp32 -> fp16 hi + fp16 lo (2-term split, exact to ~2^-22 rel)
__device__ inline void split4h(float4 p, f16x4& hv, f16x4& lv) {
  hv.x = (_Float16)p.x; hv.y = (_Float16)p.y; hv.z = (_Float16)p.z; hv.w = (_Float16)p.w;
  lv.x = (_Float16)(p.x - (float)hv.x);
  lv.y = (_Float16)(p.y - (float)hv.y);
  lv.z = (_Float16)(p.z - (float)hv.z);
  lv.w = (_Float16)(p.w - (float)hv.w);
}

// ---------------------------------------------------------------------------
// Pack W [K,512] fp32 -> MFMA B-frag layout, SINGLE fp16 plane.
// frag f = kt*32+nt (one per 16x16x32 B tile); element f*64*8 + lane*8 + j
// holds W[k,n], k = kt*32+(lane>>4)*8+j, n = nt*16+(lane&15).
// ---------------------------------------------------------------------------
__global__ __launch_bounds__(256) void pack_w_kernel(
    const float* __restrict__ W, _Float16* __restrict__ out) {
  const int tid = blockIdx.x * 256 + threadIdx.x;
  const int j = tid & 7, l = (tid >> 3) & 63, nt = (tid >> 9) & 31, kt = tid >> 14;
  const int k = kt * 32 + (l >> 4) * 8 + j;
  const int n = nt * 16 + (l & 15);
  out[tid] = (_Float16)W[k * NH + n];
}

// ---------------------------------------------------------------------------
// Fused score GEMM, asymmetric fp16 split (A: hi+lo fp16, W: single fp16):
//   score[r] = sum_n tanh((A[r,:] @ W[:,n]) + bias[n]) * pin[b,n]
// Block: 256 thr = 4 waves; M=64 rows, N=512; wave w owns cols [w*128,w*128+128),
// mt=4, nt=8, acc 128 regs -> 2 waves/SIMD (structural).
//
// JOURNAL:
//  R0 baseline (W depth-1, A depth-1, q at kt-top, __syncthreads): 183us, 33%.
//  R1 FAILED: W depth-4 circular -> 207us/28.5%. R3 FAILED: A depth-2 -> 200us/29%.
//  Diagnosis: in-order vmcnt. q (HBM, ~900cy) issued at kt TOP is OLDER than the
//  kt's W loads; the first W-wait (group 1, ~80cy later) must drain q first ->
//  ~800cy stall EVERY kt, independent of pipeline depth. __syncthreads' vmcnt(0)
//  re-drains on top. Neither R1 nor R3 touched this.
//  R4 (this): (1) issue q AFTER all W issues of the kt (sched_barrier(0) pins
//  the phase boundary) -> W-waits never drain an in-flight HBM load; q waited
//  only at next kt's STAGE, by then ~1 kt (~2500cy) old. (2) raw s_barrier +
//  lgkmcnt(0) only (no vmcnt drain) so q rides across the barrier.
// ---------------------------------------------------------------------------
template <int K>
__global__ __launch_bounds__(256, 2) void score_mfma(
    const float* __restrict__ A, const _Float16* __restrict__ Wp,
    const float* __restrict__ bias, const float* __restrict__ pin,
    float* __restrict__ score) {
  constexpr int KT = K / 32;
  __shared__ __align__(16) _Float16 lAhi[2][64 * 40];  // row stride 80 B (16B mult)
  __shared__ __align__(16) _Float16 lAlo[2][64 * 40];
  __shared__ float red[4 * 64];
  const int t = threadIdx.x;
  const int wave = t >> 6, lane = t & 63;
  const int row0 = blockIdx.x * 64;
  const int b = row0 >> 11;  // row0 / S
  const int nb = wave * 8;   // first ntile of this wave

  f32x4 acc[4][8];
#pragma unroll
  for (int mt = 0; mt < 4; ++mt)
#pragma unroll
    for (int nt = 0; nt < 8; ++nt) acc[mt][nt] = (f32x4)0.f;

  // staging: thread t loads float4 at rows {lr, lr+32}, col lc
  const int lr = t >> 3, lc = (t & 7) * 4;
  const float* Ab0 = A + (size_t)(row0 + lr) * K + lc;
  const float* Ab1 = Ab0 + (size_t)32 * K;
  const int fr = lane & 15, fq = lane >> 4;

  // W fragment stream (f16x8 = 16B units): frag f at unit f*64 + lane.
  // Depth-1 prefetch (R0 form — measured best of the depths tried).
  const f16x8* wp = (const f16x8*)Wp + (size_t)nb * 64 + lane;
  f16x8 wcur = *wp;

  // q holds the NEXT tile (kt+1) across each kt body.
  float4 q0, q1;

  {  // prologue: stage tile 0 directly, then issue q = tile 1.
    f16x4 hv, lv;
    split4h(*(const float4*)Ab0, hv, lv);
    *(f16x4*)&lAhi[0][lr * 40 + lc] = hv;
    *(f16x4*)&lAlo[0][lr * 40 + lc] = lv;
    split4h(*(const float4*)Ab1, hv, lv);
    *(f16x4*)&lAhi[0][(lr + 32) * 40 + lc] = hv;
    *(f16x4*)&lAlo[0][(lr + 32) * 40 + lc] = lv;
    if (KT > 1) {
      q0 = *(const float4*)(Ab0 + 32);
      q1 = *(const float4*)(Ab1 + 32);
    }
  }
  asm volatile("s_waitcnt lgkmcnt(0)" ::: "memory");
  __builtin_amdgcn_s_barrier();

  for (int kt = 0; kt < KT; ++kt) {
    const int cur = kt & 1;
    // LDS -> register fragments for tile kt.
    f16x8 ah[4], al[4];
#pragma unroll
    for (int mt = 0; mt < 4; ++mt) {
      const int ra = (mt * 16 + fr) * 40 + fq * 8;
      ah[mt] = *(const f16x8*)&lAhi[cur][ra];
      al[mt] = *(const f16x8*)&lAlo[cur][ra];
    }
    // 8 W-groups; all W loads of this kt (incl. next kt's group-0 frag) issue here.
#pragma unroll
    for (int nt = 0; nt < 8; ++nt) {
      const int adv = (nt < 7) ? 64 : ((kt < KT - 1) ? 25 * 64 : 0);
      const f16x8 wnxt = wp[adv];
#pragma unroll
      for (int mt = 0; mt < 4; ++mt) {
        acc[mt][nt] = __builtin_amdgcn_mfma_f32_16x16x32_f16(ah[mt], wcur, acc[mt][nt], 0, 0, 0);
        acc[mt][nt] = __builtin_amdgcn_mfma_f32_16x16x32_f16(al[mt], wcur, acc[mt][nt], 0, 0, 0);
      }
      wcur = wnxt;
      wp += adv;
    }
    // Phase boundary: nothing (esp. the HBM loads below) may move above this,
    // so no W-wait ever has an in-flight HBM load older than itself.
    __builtin_amdgcn_sched_barrier(0);
    // Issue tile kt+2 (flight window: rest of this kt + all of kt+1).
    float4 n0, n1;
    if (kt < KT - 2) {
      n0 = *(const float4*)(Ab0 + (kt + 2) * 32);
      n1 = *(const float4*)(Ab1 + (kt + 2) * 32);
    }
    // Stage tile kt+1 (q issued >= 1 kt ago; its vmcnt wait drains only
    // already-complete L2 W-loads, not the n-loads just issued).
    if (kt < KT - 1) {
      const int nxt = cur ^ 1;
      f16x4 hv, lv;
      split4h(q0, hv, lv);
      *(f16x4*)&lAhi[nxt][lr * 40 + lc] = hv;
      *(f16x4*)&lAlo[nxt][lr * 40 + lc] = lv;
      split4h(q1, hv, lv);
      *(f16x4*)&lAhi[nxt][(lr + 32) * 40 + lc] = hv;
      *(f16x4*)&lAlo[nxt][(lr + 32) * 40 + lc] = lv;
    }
    if (kt < KT - 2) { q0 = n0; q1 = n1; }
    // Raw barrier: LDS visibility via lgkmcnt(0) only; HBM n-loads stay in flight.
    asm volatile("s_waitcnt lgkmcnt(0)" ::: "memory");
    __builtin_amdgcn_s_barrier();
  }

  // Epilogue: tanh + weighted column-reduce over this wave's 128 cols.
  // C layout: col = (nb+nt)*16 + fr ; row = mt*16 + fq*4 + r.
  float ps[4][4];
#pragma unroll
  for (int mt = 0; mt < 4; ++mt)
#pragma unroll
    for (int r = 0; r < 4; ++r) ps[mt][r] = 0.f;
#pragma unroll
  for (int nt = 0; nt < 8; ++nt) {
    const int col = (nb + nt) * 16 + fr;
    const float bi = bias[col], pi = pin[b * NH + col];
#pragma unroll
    for (int mt = 0; mt < 4; ++mt)
#pragma unroll
      for (int r = 0; r < 4; ++r)
        ps[mt][r] += fast_tanh(acc[mt][nt][r] + bi) * pi;
  }
#pragma unroll
  for (int m = 8; m; m >>= 1)
#pragma unroll
    for (int mt = 0; mt < 4; ++mt)
#pragma unroll
      for (int r = 0; r < 4; ++r) ps[mt][r] += __shfl_xor(ps[mt][r], m);
  if (fr == 0)
#pragma unroll
    for (int mt = 0; mt < 4; ++mt)
#pragma unroll
      for (int r = 0; r < 4; ++r) red[wave * 64 + mt * 16 + fq * 4 + r] = ps[mt][r];
  __syncthreads();
  if (t < 64) score[row0 + t] = red[t] + red[64 + t] + red[128 + t] + red[192 + t];
}

// ---------------------------------------------------------------------------
// proj_in: tanh(input @ W_{a,b} + b_{a,b}); grid (B,4).
// ---------------------------------------------------------------------------
__global__ __launch_bounds__(256) void proj_in_kernel(
    const float* __restrict__ input,
    const float* __restrict__ W_a, const float* __restrict__ b_a,
    const float* __restrict__ W_b, const float* __restrict__ b_b,
    float* __restrict__ pa, float* __restrict__ pb) {
  __shared__ float sin_[NH];
  const int b = blockIdx.x, part = blockIdx.y, t = threadIdx.x;
  const float* W  = (part < 2) ? W_a : W_b;
  const float* bi = (part < 2) ? b_a : b_b;
  float* out      = (part < 2) ? pa : pb;
  const int h = t + (part & 1) * 256;
  sin_[t] = input[b * NH + t];
  sin_[t + 256] = input[b * NH + t + 256];
  __syncthreads();
  float acc = 0.f;
  for (int k = 0; k < NH; ++k) acc = fmaf(sin_[k], W[k * NH + h], acc);
  out[b * NH + h] = tanhf(acc + bi[h]);
}

// ---------------------------------------------------------------------------
// gamma = softmax_S(score_a + score_b)
// ---------------------------------------------------------------------------
__global__ __launch_bounds__(256) void gamma_kernel(
    const float* __restrict__ sa, const float* __restrict__ sb,
    float* __restrict__ gamma) {
  const int b = blockIdx.x, t = threadIdx.x;
  __shared__ float swp[4];
  float v[8];
  float mx = -1e30f;
#pragma unroll
  for (int i = 0; i < 8; ++i) {
    const int s = b * NS + t + i * 256;
    v[i] = sa[s] + sb[s];
    mx = fmaxf(mx, v[i]);
  }
  const int wave = t >> 6, lane = t & 63;
#pragma unroll
  for (int off = 32; off; off >>= 1) mx = fmaxf(mx, __shfl_down(mx, off));
  if (lane == 0) swp[wave] = mx;
  __syncthreads();
  mx = fmaxf(fmaxf(swp[0], swp[1]), fmaxf(swp[2], swp[3]));
  __syncthreads();
  float sum = 0.f;
#pragma unroll
  for (int i = 0; i < 8; ++i) {
    v[i] = __expf(v[i] - mx);
    sum += v[i];
  }
#pragma unroll
  for (int off = 32; off; off >>= 1) sum += __shfl_down(sum, off);
  if (lane == 0) swp[wave] = sum;
  __syncthreads();
  const float inv = 1.f / (swp[0] + swp[1] + swp[2] + swp[3]);
#pragma unroll
  for (int i = 0; i < 8; ++i) gamma[b * NS + t + i * 256] = v[i] * inv;
}

// ---------------------------------------------------------------------------
// wctx partials: grid (B,8); float4 columns; wcp has 16 chunks per batch.
// ---------------------------------------------------------------------------
__global__ __launch_bounds__(256) void wctx_kernel(
    const float* __restrict__ ctx, const float* __restrict__ gamma,
    float* __restrict__ wcp) {
  const int b = blockIdx.x, ch = blockIdx.y, t = threadIdx.x;
  __shared__ float g[256];
  const int s0 = ch * 256;
  g[t] = gamma[b * NS + s0 + t];
  __syncthreads();
  const int sh = t >> 7, h4 = (t & 127) * 4;
  float4 acc = make_float4(0.f, 0.f, 0.f, 0.f);
  const float* base = ctx + (size_t)(b * NS + s0 + sh * 128) * NH + h4;
#pragma unroll 4
  for (int s = 0; s < 128; ++s) {
    const float gs = g[sh * 128 + s];
    const float4 c = *(const float4*)(base + (size_t)s * NH);
    acc.x = fmaf(gs, c.x, acc.x);
    acc.y = fmaf(gs, c.y, acc.y);
    acc.z = fmaf(gs, c.z, acc.z);
    acc.w = fmaf(gs, c.w, acc.w);
  }
  *(float4*)&wcp[(size_t)(b * 16 + ch * 2 + sh) * NH + h4] = acc;
}

// ---------------------------------------------------------------------------
// out: reduce 16 wcp chunks -> wc; h_tilde = tanh([wc,input] @ W_out). grid (B,2).
// ---------------------------------------------------------------------------
__global__ __launch_bounds__(256) void out_kernel(
    const float* __restrict__ wcp, const float* __restrict__ input,
    const float* __restrict__ W_out, float* __restrict__ out) {
  __shared__ float cat[2 * NH];
  const int b = blockIdx.x, half = blockIdx.y, t = threadIdx.x;
  for (int i = t; i < NH; i += 256) {
    float s = 0.f;
#pragma unroll
    for (int c = 0; c < 16; ++c) s += wcp[(size_t)(b * 16 + c) * NH + i];
    cat[i] = s;
    cat[NH + i] = input[b * NH + i];
  }
  __syncthreads();
  const int o = half * 256 + t;
  float acc = 0.f;
  for (int k = 0; k < 2 * NH; ++k) acc = fmaf(cat[k], W_out[(size_t)k * NH + o], acc);
  out[b * NH + o] = tanhf(acc);
}

// ---------------------------------------------------------------------------
extern "C" void kernel_launch(void* const* d_in, const int* in_sizes, int n_in,
                              void* d_out, int out_size, void* d_ws, size_t ws_size,
                              hipStream_t stream) {
  const float* input   = (const float*)d_in[0];
  const float* context = (const float*)d_in[1];
  const float* input_z = (const float*)d_in[2];
  const float* W_enc   = (const float*)d_in[3];
  const float* b_enc   = (const float*)d_in[4];
  const float* W_a     = (const float*)d_in[5];
  const float* b_a     = (const float*)d_in[6];
  const float* W_b     = (const float*)d_in[7];
  const float* b_b     = (const float*)d_in[8];
  const float* W_z     = (const float*)d_in[9];
  const float* b_z     = (const float*)d_in[10];
  const float* W_out   = (const float*)d_in[11];

  float* out = (float*)d_out;          // [0,32768): h_tilde, then gamma
  float* ws  = (float*)d_ws;
  float* pa  = ws;                     // 32768
  float* pb  = ws + 32768;             // 32768
  float* sa  = ws + 65536;             // B*S = 131072
  float* sb  = ws + 196608;            // B*S = 131072
  float* wcp = ws + 327680;            // 64*16*512 = 524288
  _Float16* WpE = (_Float16*)(ws + 851968);   // 512*512 f16 = 512 KB
  _Float16* WpZ = (_Float16*)(ws + 983040);   // 128*512 f16 = 128 KB
  float* gamma = out + NB * NH;

  hipLaunchKernelGGL(pack_w_kernel, dim3(NH * NH / 256), dim3(256), 0, stream,
                     W_enc, WpE);
  hipLaunchKernelGGL(pack_w_kernel, dim3(NF * NH / 256), dim3(256), 0, stream,
                     W_z, WpZ);
  hipLaunchKernelGGL(proj_in_kernel, dim3(NB, 4), dim3(256), 0, stream,
                     input, W_a, b_a, W_b, b_b, pa, pb);
  hipLaunchKernelGGL(score_mfma<NH>, dim3(BS / 64), dim3(256), 0, stream,
                     context, WpE, b_enc, pa, sa);
  hipLaunchKernelGGL(score_mfma<NF>, dim3(BS / 64), dim3(256), 0, stream,
                     input_z, WpZ, b_z, pb, sb);
  hipLaunchKernelGGL(gamma_kernel, dim3(NB), dim3(256), 0, stream, sa, sb, gamma);
  hipLaunchKernelGGL(wctx_kernel, dim3(NB, 8), dim3(256), 0, stream,
                     context, gamma, wcp);
  hipLaunchKernelGGL(out_kernel, dim3(NB, 2), dim3(256), 0, stream,
                     wcp, input, W_out, out);
}

// Round 6
// 626.459 us; speedup vs baseline: 1.0634x; 1.0224x over previous
//
#include <hip/hip_runtime.h>
#include <math.h>

// DualAttention: B=64, S=2048, H=512, F=128, fp32 in/out.
#define NB 64
#define NS 2048
#define NH 512
#define NF 128
#define BS (NB * NS)

typedef __attribute__((ext_vector_type(8))) _Float16 f16x8;  // 4 VGPRs (MFMA A/B)
typedef __attribute__((ext_vector_type(4))) _Float16 f16x4;  // 8 B LDS store
typedef __attribute__((ext_vector_type(4))) float f32x4;     // MFMA C/D

__device__ inline float fast_tanh(float x) {
  float e = __expf(2.f * x);
  return 1.f - 2.f / (e + 1.f);
}
// fp32 -> fp16 hi + fp16 lo (2-term split, exact to ~2^-22 rel)
__device__ inline void split4h(float4 p, f16x4& hv, f16x4& lv) {
  hv.x = (_Float16)p.x; hv.y = (_Float16)p.y; hv.z = (_Float16)p.z; hv.w = (_Float16)p.w;
  lv.x = (_Float16)(p.x - (float)hv.x);
  lv.y = (_Float16)(p.y - (float)hv.y);
  lv.z = (_Float16)(p.z - (float)hv.z);
  lv.w = (_Float16)(p.w - (float)hv.w);
}

// ---------------------------------------------------------------------------
// Pack W [K,512] fp32 -> MFMA B-frag layout, SINGLE fp16 plane.
// frag f = kt*32+nt (one per 16x16x32 B tile); element f*64*8 + lane*8 + j
// holds W[k,n], k = kt*32+(lane>>4)*8+j, n = nt*16+(lane&15).
// ---------------------------------------------------------------------------
__global__ __launch_bounds__(256) void pack_w_kernel(
    const float* __restrict__ W, _Float16* __restrict__ out) {
  const int tid = blockIdx.x * 256 + threadIdx.x;
  const int j = tid & 7, l = (tid >> 3) & 63, nt = (tid >> 9) & 31, kt = tid >> 14;
  const int k = kt * 32 + (l >> 4) * 8 + j;
  const int n = nt * 16 + (l & 15);
  out[tid] = (_Float16)W[k * NH + n];
}

// ---------------------------------------------------------------------------
// Fused score GEMM, asymmetric fp16 split (A: hi+lo fp16, W: single fp16):
//   score[r] = sum_n tanh((A[r,:] @ W[:,n]) + bias[n]) * pin[b,n]
// Block: 256 thr = 4 waves; M=64 rows, N=512; wave w owns cols [w*128,w*128+128),
// mt=4, nt=8, acc 128 regs -> 2 waves/SIMD (structural).
//
// JOURNAL:
//  R0 baseline (W depth-1, A depth-1, q at kt-top, __syncthreads): 183us, 33%.
//  R1 FAILED: W depth-4 + q at kt-top -> 207us. R3 FAILED: A depth-2 -> 200us.
//  R4 WIN(small): issue-late q + sched_barrier + lgkm-only barrier -> 178us/34%.
//  R5 analysis: raw arithmetic says MFMA floor 49us, LDS 25us, VALU <60us ->
//  wall 178us is LATENCY: each of the 8 W-groups/kt exposes ~160cy of L2
//  latency (depth-1 W pipeline covers ~200cy with only 8 MFMA = 39cy).
//  R1 didn't disprove W-depth: its q-at-top poisoned every W wait (in-order
//  vmcnt). This round: W depth-4 UNDER R4's issue-late ordering. Refill is
//  placed AFTER each group's MFMAs (same slot -> no reg copies, WAR safe,
//  ~800cy cover), last kt peeled (no guard branch, no OOB).
// ---------------------------------------------------------------------------
template <int K>
__global__ __launch_bounds__(256, 2) void score_mfma(
    const float* __restrict__ A, const _Float16* __restrict__ Wp,
    const float* __restrict__ bias, const float* __restrict__ pin,
    float* __restrict__ score) {
  constexpr int KT = K / 32;
  __shared__ __align__(16) _Float16 lAhi[2][64 * 40];  // row stride 80 B (16B mult)
  __shared__ __align__(16) _Float16 lAlo[2][64 * 40];
  __shared__ float red[4 * 64];
  const int t = threadIdx.x;
  const int wave = t >> 6, lane = t & 63;
  const int row0 = blockIdx.x * 64;
  const int b = row0 >> 11;  // row0 / S
  const int nb = wave * 8;   // first ntile of this wave

  f32x4 acc[4][8];
#pragma unroll
  for (int mt = 0; mt < 4; ++mt)
#pragma unroll
    for (int nt = 0; nt < 8; ++nt) acc[mt][nt] = (f32x4)0.f;

  // staging: thread t loads float4 at rows {lr, lr+32}, col lc
  const int lr = t >> 3, lc = (t & 7) * 4;
  const float* Ab0 = A + (size_t)(row0 + lr) * K + lc;
  const float* Ab1 = Ab0 + (size_t)32 * K;
  const int fr = lane & 15, fq = lane >> 4;

  // W fragment stream (f16x8 = 16B units): frag (kt,nt) at unit (kt*32+nb+nt)*64
  // + lane. Depth-4 register pipeline: wbuf[p&3] holds consume-position p;
  // refill (position p+4) issues right after position p's MFMAs -> ~4 groups
  // (~800cy with 2-wave overlap) of latency cover, no older-HBM drain (q is
  // always younger under the R4 issue-late ordering).
  const f16x8* wl = (const f16x8*)Wp + (size_t)nb * 64 + lane;
  f16x8 wbuf[4];
#pragma unroll
  for (int i = 0; i < 4; ++i) {  // preload positions 0..3 (kt0, nt0..3)
    wbuf[i] = *wl;
    wl += 64;
  }  // wl now at (kt0, nt4)

  // q holds the NEXT tile (kt+1) across each kt body.
  float4 q0, q1;

  {  // prologue: stage tile 0 directly, then issue q = tile 1.
    f16x4 hv, lv;
    split4h(*(const float4*)Ab0, hv, lv);
    *(f16x4*)&lAhi[0][lr * 40 + lc] = hv;
    *(f16x4*)&lAlo[0][lr * 40 + lc] = lv;
    split4h(*(const float4*)Ab1, hv, lv);
    *(f16x4*)&lAhi[0][(lr + 32) * 40 + lc] = hv;
    *(f16x4*)&lAlo[0][(lr + 32) * 40 + lc] = lv;
    if (KT > 1) {
      q0 = *(const float4*)(Ab0 + 32);
      q1 = *(const float4*)(Ab1 + 32);
    }
  }
  asm volatile("s_waitcnt lgkmcnt(0)" ::: "memory");
  __builtin_amdgcn_s_barrier();

// One MFMA group: 8 MFMAs on wbuf slot (consume), then refill the slot with
// the fragment 4 positions ahead. REFILL=0 skips the refill (final-kt tail).
#define WGROUP(nt, REFILL)                                                     \
  {                                                                            \
    _Pragma("unroll") for (int mt = 0; mt < 4; ++mt) {                         \
      acc[mt][nt] = __builtin_amdgcn_mfma_f32_16x16x32_f16(ah[mt], wbuf[(nt)&3], acc[mt][nt], 0, 0, 0); \
      acc[mt][nt] = __builtin_amdgcn_mfma_f32_16x16x32_f16(al[mt], wbuf[(nt)&3], acc[mt][nt], 0, 0, 0); \
    }                                                                          \
    if (REFILL) {                                                              \
      wbuf[(nt)&3] = *wl;                                                      \
      wl += ((nt) == 3) ? 25 * 64 : 64;  /* loaded frag nt7 -> jump to next kt */ \
    }                                                                          \
  }

// Common kt body (fragment reads + 8 groups); REFILL_HI governs groups 4..7.
#define KT_BODY(cur, REFILL_HI)                                                \
  {                                                                            \
    f16x8 ah[4], al[4];                                                        \
    _Pragma("unroll") for (int mt = 0; mt < 4; ++mt) {                         \
      const int ra = (mt * 16 + fr) * 40 + fq * 8;                             \
      ah[mt] = *(const f16x8*)&lAhi[cur][ra];                                  \
      al[mt] = *(const f16x8*)&lAlo[cur][ra];                                  \
    }                                                                          \
    WGROUP(0, 1) WGROUP(1, 1) WGROUP(2, 1) WGROUP(3, 1)                        \
    WGROUP(4, REFILL_HI) WGROUP(5, REFILL_HI)                                  \
    WGROUP(6, REFILL_HI) WGROUP(7, REFILL_HI)                                  \
  }

  for (int kt = 0; kt < KT - 1; ++kt) {
    const int cur = kt & 1;
    KT_BODY(cur, 1)
    // Phase boundary: the HBM loads below may not move above this, so no
    // W-refill wait ever has an in-flight HBM load older than itself.
    __builtin_amdgcn_sched_barrier(0);
    // Issue tile kt+2 (flight window: rest of this kt + all of kt+1).
    float4 n0, n1;
    if (kt < KT - 2) {
      n0 = *(const float4*)(Ab0 + (kt + 2) * 32);
      n1 = *(const float4*)(Ab1 + (kt + 2) * 32);
    }
    // Stage tile kt+1 (q issued >= 1 kt ago; older than all current refills,
    // so its wait drains nothing in flight that matters).
    {
      const int nxt = cur ^ 1;
      f16x4 hv, lv;
      split4h(q0, hv, lv);
      *(f16x4*)&lAhi[nxt][lr * 40 + lc] = hv;
      *(f16x4*)&lAlo[nxt][lr * 40 + lc] = lv;
      split4h(q1, hv, lv);
      *(f16x4*)&lAhi[nxt][(lr + 32) * 40 + lc] = hv;
      *(f16x4*)&lAlo[nxt][(lr + 32) * 40 + lc] = lv;
    }
    if (kt < KT - 2) { q0 = n0; q1 = n1; }
    // Raw barrier: LDS visibility via lgkmcnt(0) only; HBM loads stay in flight.
    asm volatile("s_waitcnt lgkmcnt(0)" ::: "memory");
    __builtin_amdgcn_s_barrier();
  }
  // Final kt (peeled): positions 8(KT-1)+4 .. 8KT-1 were refilled during the
  // previous kt (groups 0..3 here load the last 4); groups 4..7 do not refill.
  KT_BODY((KT - 1) & 1, 0)
#undef WGROUP
#undef KT_BODY

  // Epilogue: tanh + weighted column-reduce over this wave's 128 cols.
  // C layout: col = (nb+nt)*16 + fr ; row = mt*16 + fq*4 + r.
  float ps[4][4];
#pragma unroll
  for (int mt = 0; mt < 4; ++mt)
#pragma unroll
    for (int r = 0; r < 4; ++r) ps[mt][r] = 0.f;
#pragma unroll
  for (int nt = 0; nt < 8; ++nt) {
    const int col = (nb + nt) * 16 + fr;
    const float bi = bias[col], pi = pin[b * NH + col];
#pragma unroll
    for (int mt = 0; mt < 4; ++mt)
#pragma unroll
      for (int r = 0; r < 4; ++r)
        ps[mt][r] += fast_tanh(acc[mt][nt][r] + bi) * pi;
  }
#pragma unroll
  for (int m = 8; m; m >>= 1)
#pragma unroll
    for (int mt = 0; mt < 4; ++mt)
#pragma unroll
      for (int r = 0; r < 4; ++r) ps[mt][r] += __shfl_xor(ps[mt][r], m);
  if (fr == 0)
#pragma unroll
    for (int mt = 0; mt < 4; ++mt)
#pragma unroll
      for (int r = 0; r < 4; ++r) red[wave * 64 + mt * 16 + fq * 4 + r] = ps[mt][r];
  __syncthreads();
  if (t < 64) score[row0 + t] = red[t] + red[64 + t] + red[128 + t] + red[192 + t];
}

// ---------------------------------------------------------------------------
// proj_in: tanh(input @ W_{a,b} + b_{a,b}); grid (B,4).
// ---------------------------------------------------------------------------
__global__ __launch_bounds__(256) void proj_in_kernel(
    const float* __restrict__ input,
    const float* __restrict__ W_a, const float* __restrict__ b_a,
    const float* __restrict__ W_b, const float* __restrict__ b_b,
    float* __restrict__ pa, float* __restrict__ pb) {
  __shared__ float sin_[NH];
  const int b = blockIdx.x, part = blockIdx.y, t = threadIdx.x;
  const float* W  = (part < 2) ? W_a : W_b;
  const float* bi = (part < 2) ? b_a : b_b;
  float* out      = (part < 2) ? pa : pb;
  const int h = t + (part & 1) * 256;
  sin_[t] = input[b * NH + t];
  sin_[t + 256] = input[b * NH + t + 256];
  __syncthreads();
  float acc = 0.f;
  for (int k = 0; k < NH; ++k) acc = fmaf(sin_[k], W[k * NH + h], acc);
  out[b * NH + h] = tanhf(acc + bi[h]);
}

// ---------------------------------------------------------------------------
// gamma = softmax_S(score_a + score_b)
// ---------------------------------------------------------------------------
__global__ __launch_bounds__(256) void gamma_kernel(
    const float* __restrict__ sa, const float* __restrict__ sb,
    float* __restrict__ gamma) {
  const int b = blockIdx.x, t = threadIdx.x;
  __shared__ float swp[4];
  float v[8];
  float mx = -1e30f;
#pragma unroll
  for (int i = 0; i < 8; ++i) {
    const int s = b * NS + t + i * 256;
    v[i] = sa[s] + sb[s];
    mx = fmaxf(mx, v[i]);
  }
  const int wave = t >> 6, lane = t & 63;
#pragma unroll
  for (int off = 32; off; off >>= 1) mx = fmaxf(mx, __shfl_down(mx, off));
  if (lane == 0) swp[wave] = mx;
  __syncthreads();
  mx = fmaxf(fmaxf(swp[0], swp[1]), fmaxf(swp[2], swp[3]));
  __syncthreads();
  float sum = 0.f;
#pragma unroll
  for (int i = 0; i < 8; ++i) {
    v[i] = __expf(v[i] - mx);
    sum += v[i];
  }
#pragma unroll
  for (int off = 32; off; off >>= 1) sum += __shfl_down(sum, off);
  if (lane == 0) swp[wave] = sum;
  __syncthreads();
  const float inv = 1.f / (swp[0] + swp[1] + swp[2] + swp[3]);
#pragma unroll
  for (int i = 0; i < 8; ++i) gamma[b * NS + t + i * 256] = v[i] * inv;
}

// ---------------------------------------------------------------------------
// wctx partials: grid (B,8); float4 columns; wcp has 16 chunks per batch.
// ---------------------------------------------------------------------------
__global__ __launch_bounds__(256) void wctx_kernel(
    const float* __restrict__ ctx, const float* __restrict__ gamma,
    float* __restrict__ wcp) {
  const int b = blockIdx.x, ch = blockIdx.y, t = threadIdx.x;
  __shared__ float g[256];
  const int s0 = ch * 256;
  g[t] = gamma[b * NS + s0 + t];
  __syncthreads();
  const int sh = t >> 7, h4 = (t & 127) * 4;
  float4 acc = make_float4(0.f, 0.f, 0.f, 0.f);
  const float* base = ctx + (size_t)(b * NS + s0 + sh * 128) * NH + h4;
#pragma unroll 4
  for (int s = 0; s < 128; ++s) {
    const float gs = g[sh * 128 + s];
    const float4 c = *(const float4*)(base + (size_t)s * NH);
    acc.x = fmaf(gs, c.x, acc.x);
    acc.y = fmaf(gs, c.y, acc.y);
    acc.z = fmaf(gs, c.z, acc.z);
    acc.w = fmaf(gs, c.w, acc.w);
  }
  *(float4*)&wcp[(size_t)(b * 16 + ch * 2 + sh) * NH + h4] = acc;
}

// ---------------------------------------------------------------------------
// out: reduce 16 wcp chunks -> wc; h_tilde = tanh([wc,input] @ W_out). grid (B,2).
// ---------------------------------------------------------------------------
__global__ __launch_bounds__(256) void out_kernel(
    const float* __restrict__ wcp, const float* __restrict__ input,
    const float* __restrict__ W_out, float* __restrict__ out) {
  __shared__ float cat[2 * NH];
  const int b = blockIdx.x, half = blockIdx.y, t = threadIdx.x;
  for (int i = t; i < NH; i += 256) {
    float s = 0.f;
#pragma unroll
    for (int c = 0; c < 16; ++c) s += wcp[(size_t)(b * 16 + c) * NH + i];
    cat[i] = s;
    cat[NH + i] = input[b * NH + i];
  }
  __syncthreads();
  const int o = half * 256 + t;
  float acc = 0.f;
  for (int k = 0; k < 2 * NH; ++k) acc = fmaf(cat[k], W_out[(size_t)k * NH + o], acc);
  out[b * NH + o] = tanhf(acc);
}

// ---------------------------------------------------------------------------
extern "C" void kernel_launch(void* const* d_in, const int* in_sizes, int n_in,
                              void* d_out, int out_size, void* d_ws, size_t ws_size,
                              hipStream_t stream) {
  const float* input   = (const float*)d_in[0];
  const float* context = (const float*)d_in[1];
  const float* input_z = (const float*)d_in[2];
  const float* W_enc   = (const float*)d_in[3];
  const float* b_enc   = (const float*)d_in[4];
  const float* W_a     = (const float*)d_in[5];
  const float* b_a     = (const float*)d_in[6];
  const float* W_b     = (const float*)d_in[7];
  const float* b_b     = (const float*)d_in[8];
  const float* W_z     = (const float*)d_in[9];
  const float* b_z     = (const float*)d_in[10];
  const float* W_out   = (const float*)d_in[11];

  float* out = (float*)d_out;          // [0,32768): h_tilde, then gamma
  float* ws  = (float*)d_ws;
  float* pa  = ws;                     // 32768
  float* pb  = ws + 32768;             // 32768
  float* sa  = ws + 65536;             // B*S = 131072
  float* sb  = ws + 196608;            // B*S = 131072
  float* wcp = ws + 327680;            // 64*16*512 = 524288
  _Float16* WpE = (_Float16*)(ws + 851968);   // 512*512 f16 = 512 KB
  _Float16* WpZ = (_Float16*)(ws + 983040);   // 128*512 f16 = 128 KB
  float* gamma = out + NB * NH;

  hipLaunchKernelGGL(pack_w_kernel, dim3(NH * NH / 256), dim3(256), 0, stream,
                     W_enc, WpE);
  hipLaunchKernelGGL(pack_w_kernel, dim3(NF * NH / 256), dim3(256), 0, stream,
                     W_z, WpZ);
  hipLaunchKernelGGL(proj_in_kernel, dim3(NB, 4), dim3(256), 0, stream,
                     input, W_a, b_a, W_b, b_b, pa, pb);
  hipLaunchKernelGGL(score_mfma<NH>, dim3(BS / 64), dim3(256), 0, stream,
                     context, WpE, b_enc, pa, sa);
  hipLaunchKernelGGL(score_mfma<NF>, dim3(BS / 64), dim3(256), 0, stream,
                     input_z, WpZ, b_z, pb, sb);
  hipLaunchKernelGGL(gamma_kernel, dim3(NB), dim3(256), 0, stream, sa, sb, gamma);
  hipLaunchKernelGGL(wctx_kernel, dim3(NB, 8), dim3(256), 0, stream,
                     context, gamma, wcp);
  hipLaunchKernelGGL(out_kernel, dim3(NB, 2), dim3(256), 0, stream,
                     wcp, input, W_out, out);
}